// Round 10
// baseline (756.412 us; speedup 1.0000x reference)
//
#include <hip/hip_runtime.h>

#define N_NODES 50000
#define N_EDGES 800000
#define HID     128
#define NGRAPH  64
#define BN_EPS  1e-5f
#define SCAN_B  98        // ceil(50000/512)
#define AGG_GRID 2048     // grid-stride agg

// ---------------- fused: degree count (E) + graph bounds (N) ----------------
__global__ __launch_bounds__(256) void degbounds_kernel(const int* __restrict__ ei,
                                                        int* __restrict__ degi,
                                                        const int* __restrict__ batch,
                                                        int* __restrict__ bound) {
    const int i = blockIdx.x * 256 + threadIdx.x;
    if (i < N_EDGES) atomicAdd(&degi[ei[N_EDGES + i]], 1);
    if (i < N_NODES) {
        const int b = batch[i];
        if (i == 0) {
            for (int g = 0; g <= b; ++g) bound[g] = 0;
        } else {
            const int pb = batch[i - 1];
            for (int g = pb + 1; g <= b; ++g) bound[g] = i;
        }
        if (i == N_NODES - 1) {
            for (int g = b + 1; g <= NGRAPH; ++g) bound[g] = N_NODES;
        }
    }
}

// ---- hierarchical exclusive scan: degi -> row_start[0..N]; also dinv = rsqrt(deg+1)
__global__ __launch_bounds__(512) void scan1_kernel(const int* __restrict__ degi,
                                                    int* __restrict__ row_start,
                                                    int* __restrict__ partials,
                                                    float* __restrict__ dinv) {
    __shared__ int sh[512];
    const int t = threadIdx.x;
    const int i = blockIdx.x * 512 + t;
    const int v = (i < N_NODES) ? degi[i] : 0;
    if (i < N_NODES) dinv[i] = rsqrtf((float)v + 1.0f);   // fused deg_fin
    sh[t] = v;
    __syncthreads();
#pragma unroll
    for (int off = 1; off < 512; off <<= 1) {
        const int add = (t >= off) ? sh[t - off] : 0;
        __syncthreads();
        sh[t] += add;
        __syncthreads();
    }
    if (i < N_NODES) row_start[i] = sh[t] - v;   // local exclusive prefix
    if (t == 511) partials[blockIdx.x] = sh[511];
}

__global__ __launch_bounds__(128) void scan2_kernel(int* __restrict__ partials,
                                                    int* __restrict__ row_start) {
    __shared__ int sh[SCAN_B + 1];
    const int t = threadIdx.x;
    if (t < SCAN_B) sh[t] = partials[t];
    __syncthreads();
    if (t == 0) {
        int run = 0;
        for (int b = 0; b < SCAN_B; ++b) { const int v = sh[b]; sh[b] = run; run += v; }
        sh[SCAN_B] = run;
    }
    __syncthreads();
    if (t < SCAN_B) partials[t] = sh[t];
    if (t == 0) row_start[N_NODES] = sh[SCAN_B];   // == E
}

__global__ __launch_bounds__(512) void scan3_kernel(int* __restrict__ row_start,
                                                    const int* __restrict__ partials) {
    const int i = blockIdx.x * 512 + threadIdx.x;
    if (i < N_NODES) row_start[i] += partials[blockIdx.x];
}

// pack (src, weight) into one 8B record
__global__ __launch_bounds__(256) void scatter_kernel(const int* __restrict__ ei,
                                                      const float* __restrict__ dinv,
                                                      const int* __restrict__ row_start,
                                                      int* __restrict__ cursor,
                                                      float2* __restrict__ csr_sw) {
    int e = blockIdx.x * 256 + threadIdx.x;
    if (e >= N_EDGES) return;
    const int src = ei[e];
    const int dst = ei[N_EDGES + e];
    const int pos = row_start[dst] + atomicAdd(&cursor[dst], 1);
    float2 sw;
    sw.x = __int_as_float(src);
    sw.y = dinv[src] * dinv[dst];
    csr_sw[pos] = sw;
}

// ---------------- GEMM: h = bnrelu(X) @ W  (64x128 tile, k-vectorized LDS) -------
// 256 thr: 4 rows x 8 cols per thread. xs col-swizzled (c4 ^ ((r>>2&3)<<2)) so the
// 4 row-group b128 k-reads hit distinct banks. LDS 49KB -> 3 blocks/CU.
__global__ __launch_bounds__(256) void gemm_kernel(const float* __restrict__ X,
                                                   const float* __restrict__ W,
                                                   const float* __restrict__ stats,
                                                   const float* __restrict__ gamma,
                                                   const float* __restrict__ beta,
                                                   const int use_bn,
                                                   float* __restrict__ hout) {
    __shared__ float xs[64][128];
    __shared__ float wsm[32][128];
    __shared__ float scs[128], shs[128];
    const int tid = threadIdx.x;
    const int block_row = blockIdx.x * 64;

    if (use_bn && tid < 128) {
        const float invN = 1.0f / (float)N_NODES;
        const float mu = stats[tid] * invN;
        const float var = stats[128 + tid] * invN - mu * mu;
        const float sc = rsqrtf(var + BN_EPS) * gamma[tid];
        scs[tid] = sc;
        shs[tid] = fmaf(-mu, sc, beta[tid]);
    }
    if (use_bn) __syncthreads();

    // stage X tile (BN+ReLU fused), swizzled store
    {
        int rows_valid = N_NODES - block_row;
        if (rows_valid > 64) rows_valid = 64;
        for (int i = tid; i < 64 * 32; i += 256) {
            const int r = i >> 5;
            const int c4 = (i & 31) * 4;
            float4 v = make_float4(0.f, 0.f, 0.f, 0.f);
            if (r < rows_valid)
                v = *(const float4*)(X + (size_t)(block_row + r) * HID + c4);
            if (use_bn) {
                const float4 sc = *(const float4*)&scs[c4];
                const float4 sh = *(const float4*)&shs[c4];
                v.x = fmaxf(fmaf(v.x, sc.x, sh.x), 0.f);
                v.y = fmaxf(fmaf(v.y, sc.y, sh.y), 0.f);
                v.z = fmaxf(fmaf(v.z, sc.z, sh.z), 0.f);
                v.w = fmaxf(fmaf(v.w, sc.w, sh.w), 0.f);
            }
            *(float4*)&xs[r][c4 ^ (((r >> 2) & 3) << 2)] = v;
        }
    }

    const int cgA = (tid & 15) * 4;            // cols cgA..+3 and cgA+64..+67
    const int r0 = (tid >> 4) * 4;             // rows r0..r0+3
    const int kswz = ((r0 >> 2) & 3) << 2;     // wave-lane swizzle (const over r0+j)

    float acc[4][8];
#pragma unroll
    for (int r = 0; r < 4; ++r)
#pragma unroll
        for (int j = 0; j < 8; ++j) acc[r][j] = 0.f;

    for (int kc = 0; kc < 4; ++kc) {
        __syncthreads();
        {
            const float4* Wv = (const float4*)(W + kc * 32 * HID);
            float4* wsv = (float4*)&wsm[0][0];
            for (int i = tid; i < 32 * 32; i += 256) wsv[i] = Wv[i];
        }
        __syncthreads();
#pragma unroll
        for (int kk4 = 0; kk4 < 32; kk4 += 4) {
            float4 xv[4];
#pragma unroll
            for (int j = 0; j < 4; ++j)
                xv[j] = *(const float4*)&xs[r0 + j][(kc * 32 + kk4) ^ kswz];
#pragma unroll
            for (int dk = 0; dk < 4; ++dk) {
                const float4 wa = *(const float4*)&wsm[kk4 + dk][cgA];
                const float4 wb = *(const float4*)&wsm[kk4 + dk][cgA + 64];
#pragma unroll
                for (int r = 0; r < 4; ++r) {
                    const float xvv = ((const float*)&xv[r])[dk];
                    acc[r][0] = fmaf(xvv, wa.x, acc[r][0]);
                    acc[r][1] = fmaf(xvv, wa.y, acc[r][1]);
                    acc[r][2] = fmaf(xvv, wa.z, acc[r][2]);
                    acc[r][3] = fmaf(xvv, wa.w, acc[r][3]);
                    acc[r][4] = fmaf(xvv, wb.x, acc[r][4]);
                    acc[r][5] = fmaf(xvv, wb.y, acc[r][5]);
                    acc[r][6] = fmaf(xvv, wb.z, acc[r][6]);
                    acc[r][7] = fmaf(xvv, wb.w, acc[r][7]);
                }
            }
        }
    }

#pragma unroll
    for (int r = 0; r < 4; ++r) {
        const int row = block_row + r0 + r;
        if (row < N_NODES) {
            float* hp = hout + (size_t)row * HID;
            *(float4*)(hp + cgA) =
                make_float4(acc[r][0], acc[r][1], acc[r][2], acc[r][3]);
            *(float4*)(hp + cgA + 64) =
                make_float4(acc[r][4], acc[r][5], acc[r][6], acc[r][7]);
        }
    }
}

// ---------------- aggregation + fused BN stats ----------------
// grid-stride (AGG_GRID blocks, 4 nodes/block/iter); per-thread register column
// sums, LDS reduce, 256 atomics/block into this layer's stats buffer.
__global__ __launch_bounds__(256) void agg_csr_kernel(const int* __restrict__ row_start,
                                                      const float2* __restrict__ csr_sw,
                                                      const float* __restrict__ h,
                                                      const float* __restrict__ dinv,
                                                      const float* __restrict__ bias,
                                                      float* __restrict__ agg,
                                                      float* __restrict__ stats_out,
                                                      const int do_stats) {
    const int lane = threadIdx.x & 63;
    const int wv = threadIdx.x >> 6;
    const int c = lane * 2;
    const float2 bv = *(const float2*)(bias + c);

    float2 ssum = make_float2(0.f, 0.f);
    float2 ssq  = make_float2(0.f, 0.f);

    for (int base = blockIdx.x * 4; base < N_NODES; base += AGG_GRID * 4) {
        const int node = base + wv;
        if (node >= N_NODES) continue;
        const int beg = row_start[node];
        const int end = row_start[node + 1];

        const float dv = dinv[node];
        const float sn = dv * dv;
        const float2 hv = *(const float2*)(h + (size_t)node * HID + c);
        float2 a0 = make_float2(fmaf(hv.x, sn, bv.x), fmaf(hv.y, sn, bv.y));
        float2 a1 = make_float2(0.f, 0.f), a2 = make_float2(0.f, 0.f),
               a3 = make_float2(0.f, 0.f), a4 = make_float2(0.f, 0.f),
               a5 = make_float2(0.f, 0.f), a6 = make_float2(0.f, 0.f),
               a7 = make_float2(0.f, 0.f);

        int p = beg;
        for (; p + 8 <= end; p += 8) {
            const float2 e0 = csr_sw[p];
            const float2 e1 = csr_sw[p + 1];
            const float2 e2 = csr_sw[p + 2];
            const float2 e3 = csr_sw[p + 3];
            const float2 e4 = csr_sw[p + 4];
            const float2 e5 = csr_sw[p + 5];
            const float2 e6 = csr_sw[p + 6];
            const float2 e7 = csr_sw[p + 7];
            const float2 v0 = *(const float2*)(h + (size_t)__float_as_int(e0.x) * HID + c);
            const float2 v1 = *(const float2*)(h + (size_t)__float_as_int(e1.x) * HID + c);
            const float2 v2 = *(const float2*)(h + (size_t)__float_as_int(e2.x) * HID + c);
            const float2 v3 = *(const float2*)(h + (size_t)__float_as_int(e3.x) * HID + c);
            const float2 v4 = *(const float2*)(h + (size_t)__float_as_int(e4.x) * HID + c);
            const float2 v5 = *(const float2*)(h + (size_t)__float_as_int(e5.x) * HID + c);
            const float2 v6 = *(const float2*)(h + (size_t)__float_as_int(e6.x) * HID + c);
            const float2 v7 = *(const float2*)(h + (size_t)__float_as_int(e7.x) * HID + c);
            a0.x = fmaf(v0.x, e0.y, a0.x); a0.y = fmaf(v0.y, e0.y, a0.y);
            a1.x = fmaf(v1.x, e1.y, a1.x); a1.y = fmaf(v1.y, e1.y, a1.y);
            a2.x = fmaf(v2.x, e2.y, a2.x); a2.y = fmaf(v2.y, e2.y, a2.y);
            a3.x = fmaf(v3.x, e3.y, a3.x); a3.y = fmaf(v3.y, e3.y, a3.y);
            a4.x = fmaf(v4.x, e4.y, a4.x); a4.y = fmaf(v4.y, e4.y, a4.y);
            a5.x = fmaf(v5.x, e5.y, a5.x); a5.y = fmaf(v5.y, e5.y, a5.y);
            a6.x = fmaf(v6.x, e6.y, a6.x); a6.y = fmaf(v6.y, e6.y, a6.y);
            a7.x = fmaf(v7.x, e7.y, a7.x); a7.y = fmaf(v7.y, e7.y, a7.y);
        }
        for (; p + 4 <= end; p += 4) {
            const float2 e0 = csr_sw[p];
            const float2 e1 = csr_sw[p + 1];
            const float2 e2 = csr_sw[p + 2];
            const float2 e3 = csr_sw[p + 3];
            const float2 v0 = *(const float2*)(h + (size_t)__float_as_int(e0.x) * HID + c);
            const float2 v1 = *(const float2*)(h + (size_t)__float_as_int(e1.x) * HID + c);
            const float2 v2 = *(const float2*)(h + (size_t)__float_as_int(e2.x) * HID + c);
            const float2 v3 = *(const float2*)(h + (size_t)__float_as_int(e3.x) * HID + c);
            a0.x = fmaf(v0.x, e0.y, a0.x); a0.y = fmaf(v0.y, e0.y, a0.y);
            a1.x = fmaf(v1.x, e1.y, a1.x); a1.y = fmaf(v1.y, e1.y, a1.y);
            a2.x = fmaf(v2.x, e2.y, a2.x); a2.y = fmaf(v2.y, e2.y, a2.y);
            a3.x = fmaf(v3.x, e3.y, a3.x); a3.y = fmaf(v3.y, e3.y, a3.y);
        }
        for (; p < end; ++p) {
            const float2 e0 = csr_sw[p];
            const float2 v0 = *(const float2*)(h + (size_t)__float_as_int(e0.x) * HID + c);
            a0.x = fmaf(v0.x, e0.y, a0.x); a0.y = fmaf(v0.y, e0.y, a0.y);
        }
        a0.x += (a1.x + a2.x) + (a3.x + a4.x) + (a5.x + a6.x) + a7.x;
        a0.y += (a1.y + a2.y) + (a3.y + a4.y) + (a5.y + a6.y) + a7.y;
        *(float2*)(agg + (size_t)node * HID + c) = a0;

        ssum.x += a0.x; ssum.y += a0.y;
        ssq.x = fmaf(a0.x, a0.x, ssq.x); ssq.y = fmaf(a0.y, a0.y, ssq.y);
    }

    if (do_stats) {
        __shared__ float s1[4][128];
        __shared__ float s2[4][128];
        s1[wv][c] = ssum.x; s1[wv][c + 1] = ssum.y;
        s2[wv][c] = ssq.x;  s2[wv][c + 1] = ssq.y;
        __syncthreads();
        const int t = threadIdx.x;
        if (t < 128) {
            atomicAdd(&stats_out[t], s1[0][t] + s1[1][t] + s1[2][t] + s1[3][t]);
        } else {
            const int c2 = t - 128;
            atomicAdd(&stats_out[128 + c2], s2[0][c2] + s2[1][c2] + s2[2][c2] + s2[3][c2]);
        }
    }
}

// ---------------- pooling: segmented (batch is sorted) ----------------
__global__ __launch_bounds__(256) void pool_seg_kernel(const float* __restrict__ a,
                                                       const int* __restrict__ bound,
                                                       float* __restrict__ z) {
    const int g = blockIdx.x;
    const int cl = threadIdx.x & 31;
    const int c = blockIdx.y * 32 + cl;
    const int par = threadIdx.x >> 5;
    const int beg = bound[g], end = bound[g + 1];
    float s = 0.f, m = 0.f;
    for (int r = beg + par; r < end; r += 8) {
        const float v = fmaxf(a[(size_t)r * HID + c], 0.f);   // layer-4 ReLU fused
        s += v;
        m = fmaxf(m, v);
    }
    __shared__ float ssum[8][32];
    __shared__ float smax[8][32];
    ssum[par][cl] = s;
    smax[par][cl] = m;
    __syncthreads();
    if (par == 0) {
        float ts = 0.f, tm = 0.f;
#pragma unroll
        for (int p = 0; p < 8; ++p) { ts += ssum[p][cl]; tm = fmaxf(tm, smax[p][cl]); }
        const float cntf = (float)(end - beg);
        z[g * 256 + c] = ts / fmaxf(cntf, 1.f);
        z[g * 256 + 128 + c] = tm;
    }
}

// ---------------- head ----------------
__global__ __launch_bounds__(128) void head_kernel(const float* __restrict__ z,
                                                   const float* __restrict__ lw1,
                                                   const float* __restrict__ lb1,
                                                   const float* __restrict__ lw2,
                                                   const float* __restrict__ lb2,
                                                   float* __restrict__ out) {
    __shared__ float zin[256];
    __shared__ float z1[128];
    const int g = blockIdx.x;
    const int t = threadIdx.x;
    zin[t] = z[g * 256 + t];
    zin[128 + t] = z[g * 256 + 128 + t];
    __syncthreads();
    float accv = lb1[t];
#pragma unroll 4
    for (int k = 0; k < 256; ++k) accv = fmaf(zin[k], lw1[k * 128 + t], accv);
    z1[t] = fmaxf(accv, 0.f);
    __syncthreads();
    if (t < 10) {
        float o = lb2[t];
#pragma unroll 4
        for (int k = 0; k < 128; ++k) o = fmaf(z1[k], lw2[k * 10 + t], o);
        out[g * 10 + t] = o;
    }
}

// ---------------- launch ----------------
extern "C" void kernel_launch(void* const* d_in, const int* in_sizes, int n_in,
                              void* d_out, int out_size, void* d_ws, size_t ws_size,
                              hipStream_t stream) {
    const float* x     = (const float*)d_in[0];
    const int*   ei    = (const int*)d_in[1];
    const int*   batch = (const int*)d_in[2];
    const float* W[4]  = {(const float*)d_in[3], (const float*)d_in[5],
                          (const float*)d_in[7], (const float*)d_in[9]};
    const float* B[4]  = {(const float*)d_in[4], (const float*)d_in[6],
                          (const float*)d_in[8], (const float*)d_in[10]};
    const float* Gm[3] = {(const float*)d_in[11], (const float*)d_in[13],
                          (const float*)d_in[15]};
    const float* Be[3] = {(const float*)d_in[12], (const float*)d_in[14],
                          (const float*)d_in[16]};
    const float* lw1 = (const float*)d_in[17];
    const float* lb1 = (const float*)d_in[18];
    const float* lw2 = (const float*)d_in[19];
    const float* lb2 = (const float*)d_in[20];

    char* ws = (char*)d_ws;
    float*  dinv      = (float*)ws;                          // @0        len 50000
    float*  stats3    = (float*)(ws + 50000u * 4);           // @50000    len 768 (3x256)
    float*  z         = (float*)(ws + 50768u * 4);           // @50768    len 16384
    int*    degi      = (int*)  (ws + 67152u * 4);           // @67152    len 50000
    int*    cursor    = (int*)  (ws + 117152u * 4);          // @117152   len 50000
    int*    row_start = (int*)  (ws + 167152u * 4);          // @167152   len 50001
    int*    bound     = (int*)  (ws + 217156u * 4);          // @217156   len 65
    float2* csr_sw    = (float2*)(ws + 217224u * 4);         // @217224   len 2*800000 (8B-aligned)
    float*  hbuf      = (float*)(ws + 1817224u * 4);         // @1817224  len 6.4M
    float*  abuf      = (float*)(ws + 8217224u * 4);         // @8217224  len 6.4M
    int*    partials  = (int*)  (ws + 14617224u * 4);        // @14617224 len 128

    // ---- CSR build (once per launch) ----
    hipMemsetAsync(degi, 0, 100000u * sizeof(int), stream);   // degi + cursor contiguous
    hipMemsetAsync(stats3, 0, 768u * sizeof(float), stream);
    degbounds_kernel<<<(N_EDGES + 255) / 256, 256, 0, stream>>>(ei, degi, batch, bound);
    scan1_kernel<<<SCAN_B, 512, 0, stream>>>(degi, row_start, partials, dinv);
    scan2_kernel<<<1, 128, 0, stream>>>(partials, row_start);
    scan3_kernel<<<SCAN_B, 512, 0, stream>>>(row_start, partials);
    scatter_kernel<<<(N_EDGES + 255) / 256, 256, 0, stream>>>(ei, dinv, row_start,
                                                              cursor, csr_sw);

    // ---- layers ----
    const float* cur = x;
    for (int l = 0; l < 4; ++l) {
        gemm_kernel<<<(N_NODES + 63) / 64, 256, 0, stream>>>(
            cur, W[l], l > 0 ? stats3 + (l - 1) * 256 : stats3,
            l > 0 ? Gm[l - 1] : Gm[0], l > 0 ? Be[l - 1] : Be[0],
            l > 0 ? 1 : 0, hbuf);
        agg_csr_kernel<<<AGG_GRID, 256, 0, stream>>>(
            row_start, csr_sw, hbuf, dinv, B[l], abuf,
            l < 3 ? stats3 + l * 256 : stats3, l < 3 ? 1 : 0);
        cur = abuf;
    }

    // ---- pooling + head ----
    pool_seg_kernel<<<dim3(NGRAPH, 4), 256, 0, stream>>>(abuf, bound, z);
    head_kernel<<<NGRAPH, 128, 0, stream>>>(z, lw1, lb1, lw2, lb2, (float*)d_out);
}

// Round 14
// 741.928 us; speedup vs baseline: 1.0195x; 1.0195x over previous
//
#include <hip/hip_runtime.h>

#define N_NODES 50000
#define N_EDGES 800000
#define HID     128
#define NGRAPH  64
#define BN_EPS  1e-5f
#define SCAN_B  98   // ceil(50000/512)

// ---------------- fused: degree count (E) + graph bounds (N) ----------------
__global__ __launch_bounds__(256) void degbounds_kernel(const int* __restrict__ ei,
                                                        int* __restrict__ degi,
                                                        const int* __restrict__ batch,
                                                        int* __restrict__ bound) {
    const int i = blockIdx.x * 256 + threadIdx.x;
    if (i < N_EDGES) atomicAdd(&degi[ei[N_EDGES + i]], 1);
    if (i < N_NODES) {
        const int b = batch[i];
        if (i == 0) {
            for (int g = 0; g <= b; ++g) bound[g] = 0;
        } else {
            const int pb = batch[i - 1];
            for (int g = pb + 1; g <= b; ++g) bound[g] = i;
        }
        if (i == N_NODES - 1) {
            for (int g = b + 1; g <= NGRAPH; ++g) bound[g] = N_NODES;
        }
    }
}

// ---- hierarchical exclusive scan: degi -> row_start[0..N]; also dinv = rsqrt(deg+1)
__global__ __launch_bounds__(512) void scan1_kernel(const int* __restrict__ degi,
                                                    int* __restrict__ row_start,
                                                    int* __restrict__ partials,
                                                    float* __restrict__ dinv) {
    __shared__ int sh[512];
    const int t = threadIdx.x;
    const int i = blockIdx.x * 512 + t;
    const int v = (i < N_NODES) ? degi[i] : 0;
    if (i < N_NODES) dinv[i] = rsqrtf((float)v + 1.0f);   // fused deg_fin
    sh[t] = v;
    __syncthreads();
#pragma unroll
    for (int off = 1; off < 512; off <<= 1) {
        const int add = (t >= off) ? sh[t - off] : 0;
        __syncthreads();
        sh[t] += add;
        __syncthreads();
    }
    if (i < N_NODES) row_start[i] = sh[t] - v;   // local exclusive prefix
    if (t == 511) partials[blockIdx.x] = sh[511];
}

__global__ __launch_bounds__(128) void scan2_kernel(int* __restrict__ partials,
                                                    int* __restrict__ row_start) {
    __shared__ int sh[SCAN_B + 1];
    const int t = threadIdx.x;
    if (t < SCAN_B) sh[t] = partials[t];
    __syncthreads();
    if (t == 0) {
        int run = 0;
        for (int b = 0; b < SCAN_B; ++b) { const int v = sh[b]; sh[b] = run; run += v; }
        sh[SCAN_B] = run;
    }
    __syncthreads();
    if (t < SCAN_B) partials[t] = sh[t];
    if (t == 0) row_start[N_NODES] = sh[SCAN_B];   // == E
}

__global__ __launch_bounds__(512) void scan3_kernel(int* __restrict__ row_start,
                                                    const int* __restrict__ partials) {
    const int i = blockIdx.x * 512 + threadIdx.x;
    if (i < N_NODES) row_start[i] += partials[blockIdx.x];
}

// pack (src, weight) into one 8B record
__global__ __launch_bounds__(256) void scatter_kernel(const int* __restrict__ ei,
                                                      const float* __restrict__ dinv,
                                                      const int* __restrict__ row_start,
                                                      int* __restrict__ cursor,
                                                      float2* __restrict__ csr_sw) {
    int e = blockIdx.x * 256 + threadIdx.x;
    if (e >= N_EDGES) return;
    const int src = ei[e];
    const int dst = ei[N_EDGES + e];
    const int pos = row_start[dst] + atomicAdd(&cursor[dst], 1);
    float2 sw;
    sw.x = __int_as_float(src);
    sw.y = dinv[src] * dinv[dst];
    csr_sw[pos] = sw;
}

// ---------------- GEMM: h = bnrelu(X) @ W  (64x128 tile, k-vectorized LDS) -------
// 256 thr: 4 rows x 8 cols per thread. xs col-swizzled (c4 ^ ((r>>2&3)<<2)) so the
// 4 row-group b128 k-reads hit distinct banks. LDS 49KB -> 3 blocks/CU.
__global__ __launch_bounds__(256) void gemm_kernel(const float* __restrict__ X,
                                                   const float* __restrict__ W,
                                                   const float* __restrict__ stats,
                                                   const float* __restrict__ gamma,
                                                   const float* __restrict__ beta,
                                                   const int use_bn,
                                                   float* __restrict__ hout) {
    __shared__ float xs[64][128];
    __shared__ float wsm[32][128];
    __shared__ float scs[128], shs[128];
    const int tid = threadIdx.x;
    const int block_row = blockIdx.x * 64;

    if (use_bn && tid < 128) {
        const float invN = 1.0f / (float)N_NODES;
        const float mu = stats[tid] * invN;
        const float var = stats[128 + tid] * invN - mu * mu;
        const float sc = rsqrtf(var + BN_EPS) * gamma[tid];
        scs[tid] = sc;
        shs[tid] = fmaf(-mu, sc, beta[tid]);
    }
    if (use_bn) __syncthreads();

    // stage X tile (BN+ReLU fused), swizzled store
    {
        int rows_valid = N_NODES - block_row;
        if (rows_valid > 64) rows_valid = 64;
        for (int i = tid; i < 64 * 32; i += 256) {
            const int r = i >> 5;
            const int c4 = (i & 31) * 4;
            float4 v = make_float4(0.f, 0.f, 0.f, 0.f);
            if (r < rows_valid)
                v = *(const float4*)(X + (size_t)(block_row + r) * HID + c4);
            if (use_bn) {
                const float4 sc = *(const float4*)&scs[c4];
                const float4 sh = *(const float4*)&shs[c4];
                v.x = fmaxf(fmaf(v.x, sc.x, sh.x), 0.f);
                v.y = fmaxf(fmaf(v.y, sc.y, sh.y), 0.f);
                v.z = fmaxf(fmaf(v.z, sc.z, sh.z), 0.f);
                v.w = fmaxf(fmaf(v.w, sc.w, sh.w), 0.f);
            }
            *(float4*)&xs[r][c4 ^ (((r >> 2) & 3) << 2)] = v;
        }
    }

    const int cgA = (tid & 15) * 4;            // cols cgA..+3 and cgA+64..+67
    const int r0 = (tid >> 4) * 4;             // rows r0..r0+3
    const int kswz = ((r0 >> 2) & 3) << 2;     // wave-lane swizzle (const over r0+j)

    float acc[4][8];
#pragma unroll
    for (int r = 0; r < 4; ++r)
#pragma unroll
        for (int j = 0; j < 8; ++j) acc[r][j] = 0.f;

    for (int kc = 0; kc < 4; ++kc) {
        __syncthreads();
        {
            const float4* Wv = (const float4*)(W + kc * 32 * HID);
            float4* wsv = (float4*)&wsm[0][0];
            for (int i = tid; i < 32 * 32; i += 256) wsv[i] = Wv[i];
        }
        __syncthreads();
#pragma unroll
        for (int kk4 = 0; kk4 < 32; kk4 += 4) {
            float4 xv[4];
#pragma unroll
            for (int j = 0; j < 4; ++j)
                xv[j] = *(const float4*)&xs[r0 + j][(kc * 32 + kk4) ^ kswz];
#pragma unroll
            for (int dk = 0; dk < 4; ++dk) {
                const float4 wa = *(const float4*)&wsm[kk4 + dk][cgA];
                const float4 wb = *(const float4*)&wsm[kk4 + dk][cgA + 64];
#pragma unroll
                for (int r = 0; r < 4; ++r) {
                    const float xvv = ((const float*)&xv[r])[dk];
                    acc[r][0] = fmaf(xvv, wa.x, acc[r][0]);
                    acc[r][1] = fmaf(xvv, wa.y, acc[r][1]);
                    acc[r][2] = fmaf(xvv, wa.z, acc[r][2]);
                    acc[r][3] = fmaf(xvv, wa.w, acc[r][3]);
                    acc[r][4] = fmaf(xvv, wb.x, acc[r][4]);
                    acc[r][5] = fmaf(xvv, wb.y, acc[r][5]);
                    acc[r][6] = fmaf(xvv, wb.z, acc[r][6]);
                    acc[r][7] = fmaf(xvv, wb.w, acc[r][7]);
                }
            }
        }
    }

#pragma unroll
    for (int r = 0; r < 4; ++r) {
        const int row = block_row + r0 + r;
        if (row < N_NODES) {
            float* hp = hout + (size_t)row * HID;
            *(float4*)(hp + cgA) =
                make_float4(acc[r][0], acc[r][1], acc[r][2], acc[r][3]);
            *(float4*)(hp + cgA + 64) =
                make_float4(acc[r][4], acc[r][5], acc[r][6], acc[r][7]);
        }
    }
}

// ---------------- aggregation: gather over CSR, one wave per dst node (R9) -------
// unroll 8: 8 independent row-gathers in flight per wave; 12500 blocks (max TLP —
// R10 showed achieved BW scales with waves in flight; do NOT grid-stride this).
__global__ __launch_bounds__(256) void agg_csr_kernel(const int* __restrict__ row_start,
                                                      const float2* __restrict__ csr_sw,
                                                      const float* __restrict__ h,
                                                      const float* __restrict__ dinv,
                                                      const float* __restrict__ bias,
                                                      float* __restrict__ agg) {
    const int node = blockIdx.x * 4 + (threadIdx.x >> 6);
    if (node >= N_NODES) return;
    const int lane = threadIdx.x & 63;
    const int c = lane * 2;
    const int beg = row_start[node];
    const int end = row_start[node + 1];

    const float dv = dinv[node];
    const float sn = dv * dv;
    const float2 hv = *(const float2*)(h + (size_t)node * HID + c);
    const float2 bv = *(const float2*)(bias + c);
    float2 a0 = make_float2(fmaf(hv.x, sn, bv.x), fmaf(hv.y, sn, bv.y));
    float2 a1 = make_float2(0.f, 0.f), a2 = make_float2(0.f, 0.f),
           a3 = make_float2(0.f, 0.f), a4 = make_float2(0.f, 0.f),
           a5 = make_float2(0.f, 0.f), a6 = make_float2(0.f, 0.f),
           a7 = make_float2(0.f, 0.f);

    int p = beg;
    for (; p + 8 <= end; p += 8) {
        const float2 e0 = csr_sw[p];
        const float2 e1 = csr_sw[p + 1];
        const float2 e2 = csr_sw[p + 2];
        const float2 e3 = csr_sw[p + 3];
        const float2 e4 = csr_sw[p + 4];
        const float2 e5 = csr_sw[p + 5];
        const float2 e6 = csr_sw[p + 6];
        const float2 e7 = csr_sw[p + 7];
        const float2 v0 = *(const float2*)(h + (size_t)__float_as_int(e0.x) * HID + c);
        const float2 v1 = *(const float2*)(h + (size_t)__float_as_int(e1.x) * HID + c);
        const float2 v2 = *(const float2*)(h + (size_t)__float_as_int(e2.x) * HID + c);
        const float2 v3 = *(const float2*)(h + (size_t)__float_as_int(e3.x) * HID + c);
        const float2 v4 = *(const float2*)(h + (size_t)__float_as_int(e4.x) * HID + c);
        const float2 v5 = *(const float2*)(h + (size_t)__float_as_int(e5.x) * HID + c);
        const float2 v6 = *(const float2*)(h + (size_t)__float_as_int(e6.x) * HID + c);
        const float2 v7 = *(const float2*)(h + (size_t)__float_as_int(e7.x) * HID + c);
        a0.x = fmaf(v0.x, e0.y, a0.x); a0.y = fmaf(v0.y, e0.y, a0.y);
        a1.x = fmaf(v1.x, e1.y, a1.x); a1.y = fmaf(v1.y, e1.y, a1.y);
        a2.x = fmaf(v2.x, e2.y, a2.x); a2.y = fmaf(v2.y, e2.y, a2.y);
        a3.x = fmaf(v3.x, e3.y, a3.x); a3.y = fmaf(v3.y, e3.y, a3.y);
        a4.x = fmaf(v4.x, e4.y, a4.x); a4.y = fmaf(v4.y, e4.y, a4.y);
        a5.x = fmaf(v5.x, e5.y, a5.x); a5.y = fmaf(v5.y, e5.y, a5.y);
        a6.x = fmaf(v6.x, e6.y, a6.x); a6.y = fmaf(v6.y, e6.y, a6.y);
        a7.x = fmaf(v7.x, e7.y, a7.x); a7.y = fmaf(v7.y, e7.y, a7.y);
    }
    for (; p + 4 <= end; p += 4) {
        const float2 e0 = csr_sw[p];
        const float2 e1 = csr_sw[p + 1];
        const float2 e2 = csr_sw[p + 2];
        const float2 e3 = csr_sw[p + 3];
        const float2 v0 = *(const float2*)(h + (size_t)__float_as_int(e0.x) * HID + c);
        const float2 v1 = *(const float2*)(h + (size_t)__float_as_int(e1.x) * HID + c);
        const float2 v2 = *(const float2*)(h + (size_t)__float_as_int(e2.x) * HID + c);
        const float2 v3 = *(const float2*)(h + (size_t)__float_as_int(e3.x) * HID + c);
        a0.x = fmaf(v0.x, e0.y, a0.x); a0.y = fmaf(v0.y, e0.y, a0.y);
        a1.x = fmaf(v1.x, e1.y, a1.x); a1.y = fmaf(v1.y, e1.y, a1.y);
        a2.x = fmaf(v2.x, e2.y, a2.x); a2.y = fmaf(v2.y, e2.y, a2.y);
        a3.x = fmaf(v3.x, e3.y, a3.x); a3.y = fmaf(v3.y, e3.y, a3.y);
    }
    for (; p < end; ++p) {
        const float2 e0 = csr_sw[p];
        const float2 v0 = *(const float2*)(h + (size_t)__float_as_int(e0.x) * HID + c);
        a0.x = fmaf(v0.x, e0.y, a0.x); a0.y = fmaf(v0.y, e0.y, a0.y);
    }
    a0.x += (a1.x + a2.x) + (a3.x + a4.x) + (a5.x + a6.x) + a7.x;
    a0.y += (a1.y + a2.y) + (a3.y + a4.y) + (a5.y + a6.y) + a7.y;
    *(float2*)(agg + (size_t)node * HID + c) = a0;
}

// ---------------- batch-norm stats (raw sums; fin folded into gemm) ----------------
__global__ __launch_bounds__(256) void bn_stats_kernel(const float* __restrict__ a,
                                                       float* __restrict__ stats) {
    const int c = threadIdx.x & 127;
    const int half = threadIdx.x >> 7;
    const int row0 = blockIdx.x * 128;
    int rend = row0 + 128;
    if (rend > N_NODES) rend = N_NODES;
    float s = 0.f, sq = 0.f;
    for (int r = row0 + half; r < rend; r += 2) {
        const float v = a[(size_t)r * HID + c];
        s += v;
        sq = fmaf(v, v, sq);
    }
    __shared__ float sh[2][2][128];
    sh[0][half][c] = s;
    sh[1][half][c] = sq;
    __syncthreads();
    if (half == 0) {
        atomicAdd(&stats[c], sh[0][0][c] + sh[0][1][c]);
        atomicAdd(&stats[HID + c], sh[1][0][c] + sh[1][1][c]);
    }
}

// ---------------- pooling: segmented (batch is sorted) ----------------
__global__ __launch_bounds__(256) void pool_seg_kernel(const float* __restrict__ a,
                                                       const int* __restrict__ bound,
                                                       float* __restrict__ z) {
    const int g = blockIdx.x;
    const int cl = threadIdx.x & 31;
    const int c = blockIdx.y * 32 + cl;
    const int par = threadIdx.x >> 5;
    const int beg = bound[g], end = bound[g + 1];
    float s = 0.f, m = 0.f;
    for (int r = beg + par; r < end; r += 8) {
        const float v = fmaxf(a[(size_t)r * HID + c], 0.f);   // layer-4 ReLU fused
        s += v;
        m = fmaxf(m, v);
    }
    __shared__ float ssum[8][32];
    __shared__ float smax[8][32];
    ssum[par][cl] = s;
    smax[par][cl] = m;
    __syncthreads();
    if (par == 0) {
        float ts = 0.f, tm = 0.f;
#pragma unroll
        for (int p = 0; p < 8; ++p) { ts += ssum[p][cl]; tm = fmaxf(tm, smax[p][cl]); }
        const float cntf = (float)(end - beg);
        z[g * 256 + c] = ts / fmaxf(cntf, 1.f);
        z[g * 256 + 128 + c] = tm;
    }
}

// ---------------- head ----------------
__global__ __launch_bounds__(128) void head_kernel(const float* __restrict__ z,
                                                   const float* __restrict__ lw1,
                                                   const float* __restrict__ lb1,
                                                   const float* __restrict__ lw2,
                                                   const float* __restrict__ lb2,
                                                   float* __restrict__ out) {
    __shared__ float zin[256];
    __shared__ float z1[128];
    const int g = blockIdx.x;
    const int t = threadIdx.x;
    zin[t] = z[g * 256 + t];
    zin[128 + t] = z[g * 256 + 128 + t];
    __syncthreads();
    float accv = lb1[t];
#pragma unroll 4
    for (int k = 0; k < 256; ++k) accv = fmaf(zin[k], lw1[k * 128 + t], accv);
    z1[t] = fmaxf(accv, 0.f);
    __syncthreads();
    if (t < 10) {
        float o = lb2[t];
#pragma unroll 4
        for (int k = 0; k < 128; ++k) o = fmaf(z1[k], lw2[k * 10 + t], o);
        out[g * 10 + t] = o;
    }
}

// ---------------- launch ----------------
extern "C" void kernel_launch(void* const* d_in, const int* in_sizes, int n_in,
                              void* d_out, int out_size, void* d_ws, size_t ws_size,
                              hipStream_t stream) {
    const float* x     = (const float*)d_in[0];
    const int*   ei    = (const int*)d_in[1];
    const int*   batch = (const int*)d_in[2];
    const float* W[4]  = {(const float*)d_in[3], (const float*)d_in[5],
                          (const float*)d_in[7], (const float*)d_in[9]};
    const float* B[4]  = {(const float*)d_in[4], (const float*)d_in[6],
                          (const float*)d_in[8], (const float*)d_in[10]};
    const float* Gm[3] = {(const float*)d_in[11], (const float*)d_in[13],
                          (const float*)d_in[15]};
    const float* Be[3] = {(const float*)d_in[12], (const float*)d_in[14],
                          (const float*)d_in[16]};
    const float* lw1 = (const float*)d_in[17];
    const float* lb1 = (const float*)d_in[18];
    const float* lw2 = (const float*)d_in[19];
    const float* lb2 = (const float*)d_in[20];

    char* ws = (char*)d_ws;
    float*  dinv      = (float*)ws;                          // @0        len 50000
    float*  stats3    = (float*)(ws + 50000u * 4);           // @50000    len 768 (3x256)
    float*  z         = (float*)(ws + 50768u * 4);           // @50768    len 16384
    int*    degi      = (int*)  (ws + 67152u * 4);           // @67152    len 50000
    int*    cursor    = (int*)  (ws + 117152u * 4);          // @117152   len 50000
    int*    row_start = (int*)  (ws + 167152u * 4);          // @167152   len 50001
    int*    bound     = (int*)  (ws + 217156u * 4);          // @217156   len 65
    float2* csr_sw    = (float2*)(ws + 217224u * 4);         // @217224   len 2*800000 (8B-aligned)
    float*  hbuf      = (float*)(ws + 1817224u * 4);         // @1817224  len 6.4M
    float*  abuf      = (float*)(ws + 8217224u * 4);         // @8217224  len 6.4M
    int*    partials  = (int*)  (ws + 14617224u * 4);        // @14617224 len 128

    // ---- CSR build (once per launch) ----
    hipMemsetAsync(degi, 0, 100000u * sizeof(int), stream);   // degi + cursor contiguous
    hipMemsetAsync(stats3, 0, 768u * sizeof(float), stream);
    degbounds_kernel<<<(N_EDGES + 255) / 256, 256, 0, stream>>>(ei, degi, batch, bound);
    scan1_kernel<<<SCAN_B, 512, 0, stream>>>(degi, row_start, partials, dinv);
    scan2_kernel<<<1, 128, 0, stream>>>(partials, row_start);
    scan3_kernel<<<SCAN_B, 512, 0, stream>>>(row_start, partials);
    scatter_kernel<<<(N_EDGES + 255) / 256, 256, 0, stream>>>(ei, dinv, row_start,
                                                              cursor, csr_sw);

    // ---- layers ----
    const float* cur = x;
    for (int l = 0; l < 4; ++l) {
        gemm_kernel<<<(N_NODES + 63) / 64, 256, 0, stream>>>(
            cur, W[l], l > 0 ? stats3 + (l - 1) * 256 : stats3,
            l > 0 ? Gm[l - 1] : Gm[0], l > 0 ? Be[l - 1] : Be[0],
            l > 0 ? 1 : 0, hbuf);
        agg_csr_kernel<<<(N_NODES + 3) / 4, 256, 0, stream>>>(row_start, csr_sw, hbuf,
                                                              dinv, B[l], abuf);
        if (l < 3)
            bn_stats_kernel<<<(N_NODES + 127) / 128, 256, 0, stream>>>(
                abuf, stats3 + l * 256);
        cur = abuf;
    }

    // ---- pooling + head ----
    pool_seg_kernel<<<dim3(NGRAPH, 4), 256, 0, stream>>>(abuf, bound, z);
    head_kernel<<<NGRAPH, 128, 0, stream>>>(z, lw1, lb1, lw2, lb2, (float*)d_out);
}